// Round 2
// baseline (341.570 us; speedup 1.0000x reference)
//
#include <hip/hip_runtime.h>
#include <hip/hip_bf16.h>
#include <cstdint>

// GateAttention fused pipeline, bf16-MFMA implementation.
// B=16, LC=2048, LQ=256, D=768, F=768.
// Round 2: big GEMMs ported to 256x256 8-phase template (T2 swizzle + T3/T4
// counted vmcnt + T5 setprio), per learn_hip m201 geometry.

using bf16 = __hip_bfloat16;
typedef __attribute__((ext_vector_type(8))) __bf16 bf16x8;
typedef __attribute__((ext_vector_type(4))) float f32x4;

typedef __attribute__((address_space(1))) const uint32_t GU32;
typedef __attribute__((address_space(3))) uint32_t LU32;

__device__ __forceinline__ void gll16(const bf16* g, bf16* l) {
  __builtin_amdgcn_global_load_lds((GU32*)g, (LU32*)l, 16, 0, 0);
}

__device__ __forceinline__ f32x4 mfma_bf16(bf16x8 a, bf16x8 b, f32x4 c) {
  return __builtin_amdgcn_mfma_f32_16x16x32_bf16(a, b, c, 0, 0, 0);
}

__device__ __forceinline__ bf16x8 ld_frag(const bf16* p) {
  return *reinterpret_cast<const bf16x8*>(p);
}

// ---------- transpose f32 [R][C] -> bf16 [C][R], batched ----------
__global__ void transpose_f32_bf16(const float* __restrict__ in, bf16* __restrict__ out,
                                   int R, int C, long ibs, long obs) {
  __shared__ float tile[32][33];
  const float* inb = in + (long)blockIdx.z * ibs;
  bf16* outb = out + (long)blockIdx.z * obs;
  int c0 = blockIdx.x * 32, r0 = blockIdx.y * 32;
  int tx = threadIdx.x, ty = threadIdx.y;
#pragma unroll
  for (int i = ty; i < 32; i += 8)
    tile[i][tx] = inb[(long)(r0 + i) * C + (c0 + tx)];
  __syncthreads();
#pragma unroll
  for (int i = ty; i < 32; i += 8)
    outb[(long)(c0 + i) * R + (r0 + tx)] = __float2bfloat16(tile[tx][i]);
}

// ---------- elementwise f32 -> bf16 with output row stride ----------
__global__ void convert_f32_bf16(const float* __restrict__ in, bf16* __restrict__ out,
                                 int cols, int ldo, long n4) {
  long i = (long)blockIdx.x * blockDim.x + threadIdx.x;
  if (i >= n4) return;
  long idx = i * 4;
  float4 v = *reinterpret_cast<const float4*>(in + idx);
  long row = idx / cols;
  int col = (int)(idx - row * cols);
  bf16* o = out + row * (long)ldo + col;
  o[0] = __float2bfloat16(v.x);
  o[1] = __float2bfloat16(v.y);
  o[2] = __float2bfloat16(v.z);
  o[3] = __float2bfloat16(v.w);
}

// ---------- legacy 128x128 GEMM (kept for the small xqW projection) ----------
template <int EPI, typename OT>
__global__ __launch_bounds__(256) void gemm_bt(
    const bf16* __restrict__ A, long lda,
    const bf16* __restrict__ Bt, long ldb,
    OT* __restrict__ Co, long ldc, int K) {
  __shared__ __align__(16) bf16 As[128 * 32];
  __shared__ __align__(16) bf16 Bs[128 * 32];
  const int tid = threadIdx.x;
  const int wave = tid >> 6;
  const int lane = tid & 63;
  const int l16 = lane & 15;
  const int kh = lane >> 4;
  const int wm = (wave >> 1) * 64;
  const int wn = (wave & 1) * 64;
  const long row0 = (long)blockIdx.x * 128;
  const long col0 = (long)blockIdx.y * 128;
  const int srow = tid >> 2;
  const int scol = (tid & 3) * 8;

  const bf16* ap0 = A + (row0 + srow) * lda + scol;
  const bf16* ap1 = ap0 + 64 * lda;
  const bf16* bp0 = Bt + (col0 + srow) * ldb + scol;
  const bf16* bp1 = bp0 + 64 * ldb;
  bf16* as0 = As + wave * 512;
  bf16* as1 = as0 + 2048;
  bf16* bs0 = Bs + wave * 512;
  bf16* bs1 = bs0 + 2048;

  f32x4 acc[4][4] = {};

  for (int k0 = 0; k0 < K; k0 += 32) {
    gll16(ap0 + k0, as0);
    gll16(ap1 + k0, as1);
    gll16(bp0 + k0, bs0);
    gll16(bp1 + k0, bs1);
    __syncthreads();
    bf16x8 af[4], bfr[4];
#pragma unroll
    for (int i = 0; i < 4; ++i)
      af[i] = ld_frag(As + (wm + i * 16 + l16) * 32 + kh * 8);
#pragma unroll
    for (int j = 0; j < 4; ++j)
      bfr[j] = ld_frag(Bs + (wn + j * 16 + l16) * 32 + kh * 8);
#pragma unroll
    for (int i = 0; i < 4; ++i)
#pragma unroll
      for (int j = 0; j < 4; ++j)
        acc[i][j] = mfma_bf16(af[i], bfr[j], acc[i][j]);
    __syncthreads();
  }

#pragma unroll
  for (int i = 0; i < 4; ++i)
#pragma unroll
    for (int j = 0; j < 4; ++j)
#pragma unroll
      for (int r = 0; r < 4; ++r) {
        long row = row0 + wm + i * 16 + kh * 4 + r;
        long col = col0 + wn + j * 16 + l16;
        float v = acc[i][j][r];
        if constexpr (EPI == 1) v = fmaxf(v, 0.0f);
        if constexpr (EPI == 2) v = 1.0f / (1.0f + expf(-v));
        if constexpr (sizeof(OT) == 2)
          Co[row * ldc + col] = __float2bfloat16(v);
        else
          Co[row * ldc + col] = (float)v;
      }
}

// ---------- 256x256 8-phase GEMM (BK=64, 8 waves 2Mx4N, dbuf LDS 128KiB) ----
// LDS per buffer: A [2 khalf][256 rows][32 k] + B [2][256][32], bf16.
// Chunk swizzle: LDS[row][chunk c] holds global chunk (c ^ (row&3)); applied
// on the global source address (linear gll16 dest) and on the ds_read addr.
// vmcnt ledger (2 gll16/wave/phase, 4 halves/tile staged 1 tile ahead):
//   end p1: vmcnt(4) -> cur tile's k-half-1 stages complete
//   end p3: vmcnt(4) -> next tile's k-half-0 stages complete
template <int EPI, typename OT>
__global__ __launch_bounds__(512, 2) void gemm8p(
    const bf16* __restrict__ A, long lda,
    const bf16* __restrict__ Bt, long ldb,
    OT* __restrict__ Co, long ldc, int K) {
  extern __shared__ __align__(16) bf16 smem[];
  const int tid = threadIdx.x;
  const int wid = tid >> 6;
  const int lane = tid & 63;
  const int l15 = lane & 15;
  const int g = lane >> 4;
  const int wm = wid >> 2;  // 0..1
  const int wn = wid & 3;   // 0..3
  const long row0 = (long)blockIdx.x * 256;
  const long col0 = (long)blockIdx.y * 256;

  const int srow = lane >> 2;                              // 0..15
  const int scol = ((lane & 3) * 8) ^ ((srow & 3) << 3);   // swizzled src chunk
  const int xcol = (g * 8) ^ ((l15 & 3) << 3);             // swizzled read chunk
  const int w16 = wid * 16;

  const bf16* Ab = A + (row0 + srow) * lda + scol;
  const bf16* Bb = Bt + (col0 + srow) * ldb + scol;

  f32x4 acc[8][4] = {};

  auto stageA = [&](int nb, int h, int kk) {
    gll16(Ab + (long)w16 * lda + kk + h * 32,
          &smem[nb * 32768 + h * 8192 + w16 * 32]);
    gll16(Ab + (long)(128 + w16) * lda + kk + h * 32,
          &smem[nb * 32768 + h * 8192 + (128 + w16) * 32]);
  };
  auto stageB = [&](int nb, int h, int kk) {
    gll16(Bb + (long)w16 * ldb + kk + h * 32,
          &smem[nb * 32768 + 16384 + h * 8192 + w16 * 32]);
    gll16(Bb + (long)(128 + w16) * ldb + kk + h * 32,
          &smem[nb * 32768 + 16384 + h * 8192 + (128 + w16) * 32]);
  };
  auto ldA = [&](int buf, int h, int m) {
    int row = wm * 128 + m * 16 + l15;
    return ld_frag(&smem[buf * 32768 + h * 8192 + row * 32 + xcol]);
  };
  auto ldB = [&](int buf, int h, int n) {
    int row = wn * 64 + n * 16 + l15;
    return ld_frag(&smem[buf * 32768 + 16384 + h * 8192 + row * 32 + xcol]);
  };

  // prologue: stage tile 0 into buffer 0, full drain once
  stageA(0, 0, 0);
  stageB(0, 0, 0);
  stageA(0, 1, 0);
  stageB(0, 1, 0);
  asm volatile("s_waitcnt vmcnt(0)\n\ts_barrier" ::: "memory");

  const int NT = K >> 6;
  int buf = 0;
  bf16x8 av[4], bv[4];

  for (int t = 0; t < NT; ++t) {
    const bool pf = (t + 1 < NT);
    const int kn = (t + 1) << 6;
    const int nb = buf ^ 1;

    // ---- phase 0: khalf 0, m 0..3 (+ all B of khalf 0) ------------------
#pragma unroll
    for (int n = 0; n < 4; ++n) bv[n] = ldB(buf, 0, n);
#pragma unroll
    for (int m = 0; m < 4; ++m) av[m] = ldA(buf, 0, m);
    if (pf) stageA(nb, 0, kn);
    __builtin_amdgcn_s_barrier();
    __builtin_amdgcn_s_setprio(1);
#pragma unroll
    for (int m = 0; m < 4; ++m)
#pragma unroll
      for (int n = 0; n < 4; ++n) acc[m][n] = mfma_bf16(av[m], bv[n], acc[m][n]);
    __builtin_amdgcn_s_setprio(0);
    __builtin_amdgcn_s_barrier();

    // ---- phase 1: khalf 0, m 4..7 ---------------------------------------
#pragma unroll
    for (int m = 0; m < 4; ++m) av[m] = ldA(buf, 0, 4 + m);
    if (pf) stageB(nb, 0, kn);
    __builtin_amdgcn_s_barrier();
    __builtin_amdgcn_s_setprio(1);
#pragma unroll
    for (int m = 0; m < 4; ++m)
#pragma unroll
      for (int n = 0; n < 4; ++n)
        acc[4 + m][n] = mfma_bf16(av[m], bv[n], acc[4 + m][n]);
    __builtin_amdgcn_s_setprio(0);
    if (pf)
      asm volatile("s_waitcnt vmcnt(4)\n\ts_barrier" ::: "memory");
    else
      asm volatile("s_waitcnt vmcnt(0)\n\ts_barrier" ::: "memory");

    // ---- phase 2: khalf 1, m 0..3 (+ all B of khalf 1) ------------------
#pragma unroll
    for (int n = 0; n < 4; ++n) bv[n] = ldB(buf, 1, n);
#pragma unroll
    for (int m = 0; m < 4; ++m) av[m] = ldA(buf, 1, m);
    if (pf) stageA(nb, 1, kn);
    __builtin_amdgcn_s_barrier();
    __builtin_amdgcn_s_setprio(1);
#pragma unroll
    for (int m = 0; m < 4; ++m)
#pragma unroll
      for (int n = 0; n < 4; ++n) acc[m][n] = mfma_bf16(av[m], bv[n], acc[m][n]);
    __builtin_amdgcn_s_setprio(0);
    __builtin_amdgcn_s_barrier();

    // ---- phase 3: khalf 1, m 4..7 ---------------------------------------
#pragma unroll
    for (int m = 0; m < 4; ++m) av[m] = ldA(buf, 1, 4 + m);
    if (pf) stageB(nb, 1, kn);
    __builtin_amdgcn_s_barrier();
    __builtin_amdgcn_s_setprio(1);
#pragma unroll
    for (int m = 0; m < 4; ++m)
#pragma unroll
      for (int n = 0; n < 4; ++n)
        acc[4 + m][n] = mfma_bf16(av[m], bv[n], acc[4 + m][n]);
    __builtin_amdgcn_s_setprio(0);
    if (pf)
      asm volatile("s_waitcnt vmcnt(4)\n\ts_barrier" ::: "memory");
    else
      __builtin_amdgcn_s_barrier();

    buf = nb;
  }

  // epilogue
#pragma unroll
  for (int m = 0; m < 8; ++m)
#pragma unroll
    for (int n = 0; n < 4; ++n)
#pragma unroll
      for (int r = 0; r < 4; ++r) {
        long row = row0 + wm * 128 + m * 16 + g * 4 + r;
        long col = col0 + wn * 64 + n * 16 + l15;
        float v = acc[m][n][r];
        if constexpr (EPI == 1) v = fmaxf(v, 0.0f);
        if constexpr (EPI == 2) v = 1.0f / (1.0f + expf(-v));
        if constexpr (sizeof(OT) == 2)
          Co[row * ldc + col] = __float2bfloat16(v);
        else
          Co[row * ldc + col] = (float)v;
      }
}

// ---------- fused attention: per (b, 64-row c-tile) ----------
__global__ __launch_bounds__(256) void attn_kernel(
    const bf16* __restrict__ xcW, const bf16* __restrict__ xqW,
    const bf16* __restrict__ xqT, const int* __restrict__ qlen_arr,
    bf16* __restrict__ res) {
  __shared__ __align__(16) bf16 As[64 * 32];
  __shared__ __align__(16) bf16 Bs[256 * 32];
  __shared__ __align__(16) bf16 P[64 * 264];  // padded stride 264
  __shared__ float wred[64][4];
  __shared__ float wsum[64][4];

  const int b = blockIdx.y;
  const int ct = blockIdx.x;
  const int tid = threadIdx.x;
  const int wave = tid >> 6;
  const int lane = tid & 63;
  const int l16 = lane & 15;
  const int kh = lane >> 4;

  const long crow0 = (long)b * 2048 + (long)ct * 64;
  const int srow = tid >> 2;
  const int scol = (tid & 3) * 8;

  const bf16* ap = xcW + (crow0 + srow) * 768 + scol;
  const bf16* bp = xqW + ((long)b * 256 + srow) * 768 + scol;

  f32x4 acc[4][4] = {};
  for (int k0 = 0; k0 < 768; k0 += 32) {
    gll16(ap + k0, As + wave * 512);
    gll16(bp + k0, Bs + wave * 512);
    gll16(bp + 64 * 768 + k0, Bs + 2048 + wave * 512);
    gll16(bp + 128 * 768 + k0, Bs + 4096 + wave * 512);
    gll16(bp + 192 * 768 + k0, Bs + 6144 + wave * 512);
    __syncthreads();
    bf16x8 af[4], bfr[4];
#pragma unroll
    for (int i = 0; i < 4; ++i)
      af[i] = ld_frag(As + (i * 16 + l16) * 32 + kh * 8);
#pragma unroll
    for (int j = 0; j < 4; ++j)
      bfr[j] = ld_frag(Bs + (wave * 64 + j * 16 + l16) * 32 + kh * 8);
#pragma unroll
    for (int i = 0; i < 4; ++i)
#pragma unroll
      for (int j = 0; j < 4; ++j)
        acc[i][j] = mfma_bf16(af[i], bfr[j], acc[i][j]);
    __syncthreads();
  }

  const float scale = 0.036084391824351615f;  // 1/sqrt(768)
  const int qlen = qlen_arr[b];

#pragma unroll
  for (int i = 0; i < 4; ++i)
#pragma unroll
    for (int j = 0; j < 4; ++j) {
      int col = wave * 64 + j * 16 + l16;
      float m = (col >= qlen) ? -1.0e12f : 0.0f;
#pragma unroll
      for (int r = 0; r < 4; ++r)
        acc[i][j][r] = acc[i][j][r] * scale + m;
    }

#pragma unroll
  for (int i = 0; i < 4; ++i)
#pragma unroll
    for (int r = 0; r < 4; ++r) {
      float mx = fmaxf(fmaxf(acc[i][0][r], acc[i][1][r]),
                       fmaxf(acc[i][2][r], acc[i][3][r]));
      mx = fmaxf(mx, __shfl_xor(mx, 1));
      mx = fmaxf(mx, __shfl_xor(mx, 2));
      mx = fmaxf(mx, __shfl_xor(mx, 4));
      mx = fmaxf(mx, __shfl_xor(mx, 8));
      if (l16 == 0) wred[i * 16 + kh * 4 + r][wave] = mx;
    }
  __syncthreads();

#pragma unroll
  for (int i = 0; i < 4; ++i)
#pragma unroll
    for (int r = 0; r < 4; ++r) {
      int row = i * 16 + kh * 4 + r;
      float gm = fmaxf(fmaxf(wred[row][0], wred[row][1]),
                       fmaxf(wred[row][2], wred[row][3]));
      float s = 0.0f;
#pragma unroll
      for (int j = 0; j < 4; ++j) {
        float e = expf(acc[i][j][r] - gm);
        acc[i][j][r] = e;
        s += e;
      }
      s += __shfl_xor(s, 1);
      s += __shfl_xor(s, 2);
      s += __shfl_xor(s, 4);
      s += __shfl_xor(s, 8);
      if (l16 == 0) wsum[row][wave] = s;
    }
  __syncthreads();

#pragma unroll
  for (int i = 0; i < 4; ++i)
#pragma unroll
    for (int r = 0; r < 4; ++r) {
      int row = i * 16 + kh * 4 + r;
      float inv = 1.0f / (wsum[row][0] + wsum[row][1] + wsum[row][2] + wsum[row][3]);
#pragma unroll
      for (int j = 0; j < 4; ++j)
        P[row * 264 + wave * 64 + j * 16 + l16] = __float2bfloat16(acc[i][j][r] * inv);
    }
  __syncthreads();

  for (int nb = 0; nb < 3; ++nb) {
    const int n0 = nb * 256 + wave * 64;
    const bf16* btp = xqT + ((long)b * 768 + n0) * 256;
    f32x4 a2[4][4] = {};
#pragma unroll
    for (int kk = 0; kk < 256; kk += 32) {
      bf16x8 pf[4], vf[4];
#pragma unroll
      for (int i = 0; i < 4; ++i)
        pf[i] = ld_frag(P + (i * 16 + l16) * 264 + kk + kh * 8);
#pragma unroll
      for (int j = 0; j < 4; ++j)
        vf[j] = ld_frag(btp + (j * 16 + l16) * 256 + kk + kh * 8);
#pragma unroll
      for (int i = 0; i < 4; ++i)
#pragma unroll
        for (int j = 0; j < 4; ++j)
          a2[i][j] = mfma_bf16(pf[i], vf[j], a2[i][j]);
    }
#pragma unroll
    for (int i = 0; i < 4; ++i)
#pragma unroll
      for (int j = 0; j < 4; ++j)
#pragma unroll
        for (int r = 0; r < 4; ++r) {
          long row = crow0 + i * 16 + kh * 4 + r;
          int col = n0 + j * 16 + l16;
          res[row * 1536 + 768 + col] = __float2bfloat16(a2[i][j][r]);
        }
  }
}

extern "C" void kernel_launch(void* const* d_in, const int* in_sizes, int n_in,
                              void* d_out, int out_size, void* d_ws, size_t ws_size,
                              hipStream_t stream) {
  const float* x_cont = (const float*)d_in[0];  // [16,2048,768]
  const float* x_ques = (const float*)d_in[1];  // [16,256,768]
  const int* ques_len = (const int*)d_in[2];    // [16]
  const float* WC = (const float*)d_in[3];      // [768,768]
  const float* WQ = (const float*)d_in[4];      // [768,768]
  const float* V = (const float*)d_in[5];       // [1536,768]
  float* out = (float*)d_out;                   // [32768,768]

  bf16* WCt = (bf16*)d_ws;                      // [768][768]
  bf16* WQt = WCt + (long)768 * 768;            // [768][768]
  bf16* Vt = WQt + (long)768 * 768;             // [768][1536]
  bf16* xqB = Vt + (long)768 * 1536;            // [4096][768]
  bf16* xqT = xqB + (long)4096 * 768;           // [16][768][256]
  bf16* xqW = xqT + (long)16 * 768 * 256;       // [4096][768]
  bf16* xcW = xqW + (long)4096 * 768;           // [32768][768]
  bf16* res = xcW + (long)32768 * 768;          // [32768][1536]

  (void)hipFuncSetAttribute(reinterpret_cast<const void*>(&gemm8p<1, bf16>),
                            hipFuncAttributeMaxDynamicSharedMemorySize, 131072);
  (void)hipFuncSetAttribute(reinterpret_cast<const void*>(&gemm8p<2, float>),
                            hipFuncAttributeMaxDynamicSharedMemorySize, 131072);

  // weight / input conversions
  transpose_f32_bf16<<<dim3(24, 24, 1), dim3(32, 8), 0, stream>>>(WC, WCt, 768, 768, 0, 0);
  transpose_f32_bf16<<<dim3(24, 24, 1), dim3(32, 8), 0, stream>>>(WQ, WQt, 768, 768, 0, 0);
  transpose_f32_bf16<<<dim3(24, 48, 1), dim3(32, 8), 0, stream>>>(V, Vt, 1536, 768, 0, 0);
  transpose_f32_bf16<<<dim3(24, 8, 16), dim3(32, 8), 0, stream>>>(
      x_ques, xqT, 256, 768, (long)256 * 768, (long)768 * 256);
  convert_f32_bf16<<<3072, 256, 0, stream>>>(x_ques, xqB, 768, 768, (long)4096 * 768 / 4);
  convert_f32_bf16<<<24576, 256, 0, stream>>>(x_cont, res, 768, 1536, (long)32768 * 768 / 4);

  // projections
  gemm_bt<1, bf16><<<dim3(32, 6), 256, 0, stream>>>(xqB, 768, WQt, 768, xqW, 768, 768);
  gemm8p<1, bf16><<<dim3(128, 3), 512, 131072, stream>>>(res, 1536, WCt, 768, xcW, 768, 768);

  // attention -> C into right half of res
  attn_kernel<<<dim3(32, 16), 256, 0, stream>>>(xcW, xqW, xqT, ques_len, res);

  // gate = sigmoid(res @ V)
  gemm8p<2, float><<<dim3(128, 3), 512, 131072, stream>>>(res, 1536, Vt, 1536, out, 768, 1536);
}

// Round 3
// 287.777 us; speedup vs baseline: 1.1869x; 1.1869x over previous
//
#include <hip/hip_runtime.h>
#include <hip/hip_bf16.h>
#include <cstdint>

// GateAttention, restructured:
//   xcW|G1 = xc @ [WC | V_top]   (relu on xcW half; G1 -> d_out f32)
//   xqW|xqV = xq @ [WQ | V_bot]  (relu on xqW half)
//   attn: S = xcW.xqW^T, softmax+mask, O = P @ xqV, out = sigmoid(G1 + O)
// This uses attn@(xq@Vbot) == (attn@xq)@Vbot to delete 38.7 GFLOP and the
// res/C buffers entirely.
// B=16, LC=2048, LQ=256, D=768, F=768.

using bf16 = __hip_bfloat16;
typedef __attribute__((ext_vector_type(8))) __bf16 bf16x8;
typedef __attribute__((ext_vector_type(4))) float f32x4;

typedef __attribute__((address_space(1))) const uint32_t GU32;
typedef __attribute__((address_space(3))) uint32_t LU32;

__device__ __forceinline__ void gll16(const bf16* g, bf16* l) {
  __builtin_amdgcn_global_load_lds((GU32*)g, (LU32*)l, 16, 0, 0);
}
__device__ __forceinline__ f32x4 mfma_bf16(bf16x8 a, bf16x8 b, f32x4 c) {
  return __builtin_amdgcn_mfma_f32_16x16x32_bf16(a, b, c, 0, 0, 0);
}
__device__ __forceinline__ bf16x8 ld_frag(const bf16* p) {
  return *reinterpret_cast<const bf16x8*>(p);
}
// LDS chunk swizzle: conflict-free for stride-64B rows under 8-lane beats.
__device__ __forceinline__ int swz(int r) { return (r & 3) ^ ((r >> 2) & 1); }

__device__ __forceinline__ unsigned short f2bf_bits(float x) {
  bf16 b = __float2bfloat16(x);
  union { bf16 b; unsigned short s; } u;
  u.b = b;
  return u.s;
}

// ---------- transpose f32 [R][C] -> bf16 [C][R] ----------
__global__ void transpose_f32_bf16(const float* __restrict__ in, bf16* __restrict__ out,
                                   int R, int C) {
  __shared__ float tile[32][33];
  int c0 = blockIdx.x * 32, r0 = blockIdx.y * 32;
  int tx = threadIdx.x, ty = threadIdx.y;
#pragma unroll
  for (int i = ty; i < 32; i += 8)
    tile[i][tx] = in[(long)(r0 + i) * C + (c0 + tx)];
  __syncthreads();
#pragma unroll
  for (int i = ty; i < 32; i += 8)
    out[(long)(c0 + i) * R + (r0 + tx)] = __float2bfloat16(tile[tx][i]);
}

// ---------- transpose bf16 [R][C] -> bf16 [C][R], batched ----------
__global__ void transpose_bf16(const bf16* __restrict__ in, bf16* __restrict__ out,
                               int R, int C, long ibs, long obs) {
  __shared__ bf16 tile[32][33];
  const bf16* inb = in + (long)blockIdx.z * ibs;
  bf16* outb = out + (long)blockIdx.z * obs;
  int c0 = blockIdx.x * 32, r0 = blockIdx.y * 32;
  int tx = threadIdx.x, ty = threadIdx.y;
#pragma unroll
  for (int i = ty; i < 32; i += 8)
    tile[i][tx] = inb[(long)(r0 + i) * C + (c0 + tx)];
  __syncthreads();
#pragma unroll
  for (int i = ty; i < 32; i += 8)
    outb[(long)(c0 + i) * R + (r0 + tx)] = tile[tx][i];
}

// ---------- flat f32 -> bf16 convert, 8B stores ----------
__global__ void convert_flat(const float* __restrict__ in, bf16* __restrict__ out, long n4) {
  long i = (long)blockIdx.x * blockDim.x + threadIdx.x;
  if (i >= n4) return;
  float4 v = reinterpret_cast<const float4*>(in)[i];
  ushort4 o;
  o.x = f2bf_bits(v.x);
  o.y = f2bf_bits(v.y);
  o.z = f2bf_bits(v.z);
  o.w = f2bf_bits(v.w);
  reinterpret_cast<ushort4*>(out)[i] = o;
}

// ---------- 128x128 GEMM with split epilogue (for the small xq projection) --
// cols [0,768): relu -> O1 bf16 ; cols [768,1536): plain -> O2 bf16.
__global__ __launch_bounds__(256) void gemm_bt_split(
    const bf16* __restrict__ A, long lda,
    const bf16* __restrict__ Bt, long ldb,
    bf16* __restrict__ O1, bf16* __restrict__ O2, int K) {
  __shared__ __align__(16) bf16 As[128 * 32];
  __shared__ __align__(16) bf16 Bs[128 * 32];
  const int tid = threadIdx.x;
  const int wave = tid >> 6;
  const int lane = tid & 63;
  const int l16 = lane & 15;
  const int kh = lane >> 4;
  const int wm = (wave >> 1) * 64;
  const int wn = (wave & 1) * 64;
  const long row0 = (long)blockIdx.x * 128;
  const long col0 = (long)blockIdx.y * 128;
  const int srow = tid >> 2;
  const int scol = ((tid & 3) ^ swz(srow)) * 8;
  const int xcol = 0;  // computed per-read below

  const bf16* ap0 = A + (row0 + srow) * lda + scol;
  const bf16* ap1 = ap0 + 64 * lda;
  const bf16* bp0 = Bt + (col0 + srow) * ldb + scol;
  const bf16* bp1 = bp0 + 64 * ldb;
  bf16* as0 = As + wave * 512;
  bf16* as1 = as0 + 2048;
  bf16* bs0 = Bs + wave * 512;
  bf16* bs1 = bs0 + 2048;

  const int xc = (kh ^ swz(l16)) * 8;
  (void)xcol;
  f32x4 acc[4][4] = {};

  for (int k0 = 0; k0 < K; k0 += 32) {
    gll16(ap0 + k0, as0);
    gll16(ap1 + k0, as1);
    gll16(bp0 + k0, bs0);
    gll16(bp1 + k0, bs1);
    __syncthreads();
    bf16x8 af[4], bfr[4];
#pragma unroll
    for (int i = 0; i < 4; ++i)
      af[i] = ld_frag(As + (wm + i * 16 + l16) * 32 + xc);
#pragma unroll
    for (int j = 0; j < 4; ++j)
      bfr[j] = ld_frag(Bs + (wn + j * 16 + l16) * 32 + xc);
#pragma unroll
    for (int i = 0; i < 4; ++i)
#pragma unroll
      for (int j = 0; j < 4; ++j)
        acc[i][j] = mfma_bf16(af[i], bfr[j], acc[i][j]);
    __syncthreads();
  }

  const bool isO1 = col0 < 768;
#pragma unroll
  for (int i = 0; i < 4; ++i)
#pragma unroll
    for (int j = 0; j < 4; ++j)
#pragma unroll
      for (int r = 0; r < 4; ++r) {
        long row = row0 + wm + i * 16 + kh * 4 + r;
        long col = col0 + wn + j * 16 + l16;
        float v = acc[i][j][r];
        if (isO1)
          O1[row * 768 + col] = __float2bfloat16(fmaxf(v, 0.0f));
        else
          O2[row * 768 + (col - 768)] = __float2bfloat16(v);
      }
}

// ---------- 256x256 GEMM, BK=32, 4-buffer LDS, 3-tile prefetch depth -------
// M=32768, N=1536 (6 tiles), K=768 (24 K-tiles). Grid: 768 blocks (1D).
// cols [0,768): relu -> O1 bf16 (xcW) ; cols [768,1536): plain -> O2 f32 (G1).
__global__ __launch_bounds__(512, 2) void gemm4b(
    const bf16* __restrict__ A, long lda,
    const bf16* __restrict__ Bt, long ldb,
    bf16* __restrict__ O1, float* __restrict__ O2, int K) {
  extern __shared__ __align__(16) bf16 smem[];  // 4 bufs x (A 8192 + B 8192) bf16
  const int tid = threadIdx.x;
  const int wid = tid >> 6;
  const int lane = tid & 63;
  const int l15 = lane & 15;
  const int g = lane >> 4;
  const int wm = wid >> 2;  // 0..1
  const int wn = wid & 3;   // 0..3

  // XCD-chunked bijective block swizzle (768 % 8 == 0): each XCD gets a
  // contiguous run of wgids -> the 6 blocks sharing an A-panel co-locate.
  const int lin = blockIdx.x;          // 0..767
  const int per = (int)gridDim.x >> 3; // 96
  const int wgid = (lin & 7) * per + (lin >> 3);
  const long row0 = (long)(wgid / 6) * 256;
  const long col0 = (long)(wgid % 6) * 256;

  const int srow = lane >> 2;                       // 0..15
  const int sc = ((lane & 3) ^ swz(srow)) * 8;      // swizzled src chunk
  const int w16 = wid * 16;
  const bf16* Ab = A + (row0 + srow) * lda + sc;
  const bf16* Bb = Bt + (col0 + srow) * ldb + sc;

  f32x4 acc[8][4] = {};

  auto stageA = [&](int buf, int kk) {
    bf16* d = smem + buf * 16384 + w16 * 32;
    gll16(Ab + (long)w16 * lda + kk, d);
    gll16(Ab + (long)(128 + w16) * lda + kk, d + 128 * 32);
  };
  auto stageB = [&](int buf, int kk) {
    bf16* d = smem + buf * 16384 + 8192 + w16 * 32;
    gll16(Bb + (long)w16 * ldb + kk, d);
    gll16(Bb + (long)(128 + w16) * ldb + kk, d + 128 * 32);
  };
  const int xc = (g ^ swz(l15)) * 8;
  auto ldA = [&](int buf, int m) {
    int row = wm * 128 + m * 16 + l15;
    return ld_frag(smem + buf * 16384 + row * 32 + xc);
  };
  auto ldB = [&](int buf, int n) {
    int row = wn * 64 + n * 16 + l15;
    return ld_frag(smem + buf * 16384 + 8192 + row * 32 + xc);
  };

  // prologue: stage tiles 0,1,2 (12 gll16/wave); wait tile 0 (vmcnt 8 left)
  stageA(0, 0);
  stageB(0, 0);
  stageA(1, 32);
  stageB(1, 32);
  stageA(2, 64);
  stageB(2, 64);
  asm volatile("s_waitcnt vmcnt(8)\n\ts_barrier" ::: "memory");

  const int NT = K >> 5;  // 24
  bf16x8 av[4], bv[4];

  for (int t = 0; t < NT; ++t) {
    const int cur = t & 3;
    const int pfb = (t + 3) & 3;
    const bool pf = (t + 3) < NT;
    const int kk = (t + 3) << 5;

    // ---- phase 0: m 0..3 (+ all B frags) + prefetch A(t+3) ----
#pragma unroll
    for (int n = 0; n < 4; ++n) bv[n] = ldB(cur, n);
#pragma unroll
    for (int m = 0; m < 4; ++m) av[m] = ldA(cur, m);
    if (pf) stageA(pfb, kk);
    __builtin_amdgcn_s_barrier();
    __builtin_amdgcn_s_setprio(1);
#pragma unroll
    for (int m = 0; m < 4; ++m)
#pragma unroll
      for (int n = 0; n < 4; ++n) acc[m][n] = mfma_bf16(av[m], bv[n], acc[m][n]);
    __builtin_amdgcn_s_setprio(0);
    __builtin_amdgcn_s_barrier();

    // ---- phase 1: m 4..7 + prefetch B(t+3) ----
#pragma unroll
    for (int m = 0; m < 4; ++m) av[m] = ldA(cur, 4 + m);
    if (pf) stageB(pfb, kk);
    __builtin_amdgcn_s_barrier();
    __builtin_amdgcn_s_setprio(1);
#pragma unroll
    for (int m = 0; m < 4; ++m)
#pragma unroll
      for (int n = 0; n < 4; ++n)
        acc[4 + m][n] = mfma_bf16(av[m], bv[n], acc[4 + m][n]);
    __builtin_amdgcn_s_setprio(0);

    // ---- end-of-tile: ensure tile t+1 staged; keep deeper loads in flight
    if (t <= NT - 4)
      asm volatile("s_waitcnt vmcnt(8)\n\ts_barrier" ::: "memory");
    else if (t == NT - 3)
      asm volatile("s_waitcnt vmcnt(4)\n\ts_barrier" ::: "memory");
    else if (t == NT - 2)
      asm volatile("s_waitcnt vmcnt(0)\n\ts_barrier" ::: "memory");
    // t == NT-1: fall through to epilogue
  }

  const bool isO1 = col0 < 768;
#pragma unroll
  for (int m = 0; m < 8; ++m)
#pragma unroll
    for (int n = 0; n < 4; ++n)
#pragma unroll
      for (int r = 0; r < 4; ++r) {
        long row = row0 + wm * 128 + m * 16 + g * 4 + r;
        long col = col0 + wn * 64 + n * 16 + l15;
        float v = acc[m][n][r];
        if (isO1)
          O1[row * 768 + col] = __float2bfloat16(fmaxf(v, 0.0f));
        else
          O2[row * 768 + (col - 768)] = v;
      }
}

// ---------- fused attention + gate epilogue: per (b, 64-row c-tile) --------
// S = xcW_tile @ xqW[b]^T * scale + mask ; P = softmax(S)
// O = P @ xqV[b] ; out = sigmoid(G1 + O)  (G1 pre-stored in out, f32)
__global__ __launch_bounds__(256) void attn_kernel(
    const bf16* __restrict__ xcW, const bf16* __restrict__ xqW,
    const bf16* __restrict__ xqVT, const int* __restrict__ qlen_arr,
    float* __restrict__ out) {
  __shared__ __align__(16) bf16 As[64 * 32];
  __shared__ __align__(16) bf16 Bs[256 * 32];
  __shared__ __align__(16) bf16 P[64 * 264];  // padded stride 264
  __shared__ float wred[64][4];
  __shared__ float wsum[64][4];

  const int b = blockIdx.y;
  const int ct = blockIdx.x;
  const int tid = threadIdx.x;
  const int wave = tid >> 6;
  const int lane = tid & 63;
  const int l16 = lane & 15;
  const int kh = lane >> 4;

  const long crow0 = (long)b * 2048 + (long)ct * 64;
  const int srow = tid >> 2;
  const int scol = ((tid & 3) ^ swz(srow)) * 8;

  const bf16* ap = xcW + (crow0 + srow) * 768 + scol;
  const bf16* bp = xqW + ((long)b * 256 + srow) * 768 + scol;
  const int xc = (kh ^ swz(l16)) * 8;

  f32x4 acc[4][4] = {};
  for (int k0 = 0; k0 < 768; k0 += 32) {
    gll16(ap + k0, As + wave * 512);
    gll16(bp + k0, Bs + wave * 512);
    gll16(bp + 64 * 768 + k0, Bs + 2048 + wave * 512);
    gll16(bp + 128 * 768 + k0, Bs + 4096 + wave * 512);
    gll16(bp + 192 * 768 + k0, Bs + 6144 + wave * 512);
    __syncthreads();
    bf16x8 af[4], bfr[4];
#pragma unroll
    for (int i = 0; i < 4; ++i)
      af[i] = ld_frag(As + (i * 16 + l16) * 32 + xc);
#pragma unroll
    for (int j = 0; j < 4; ++j)
      bfr[j] = ld_frag(Bs + (wave * 64 + j * 16 + l16) * 32 + xc);
#pragma unroll
    for (int i = 0; i < 4; ++i)
#pragma unroll
      for (int j = 0; j < 4; ++j)
        acc[i][j] = mfma_bf16(af[i], bfr[j], acc[i][j]);
    __syncthreads();
  }

  const float scale = 0.036084391824351615f;  // 1/sqrt(768)
  const int qlen = qlen_arr[b];

#pragma unroll
  for (int i = 0; i < 4; ++i)
#pragma unroll
    for (int j = 0; j < 4; ++j) {
      int col = wave * 64 + j * 16 + l16;
      float m = (col >= qlen) ? -1.0e12f : 0.0f;
#pragma unroll
      for (int r = 0; r < 4; ++r)
        acc[i][j][r] = acc[i][j][r] * scale + m;
    }

#pragma unroll
  for (int i = 0; i < 4; ++i)
#pragma unroll
    for (int r = 0; r < 4; ++r) {
      float mx = fmaxf(fmaxf(acc[i][0][r], acc[i][1][r]),
                       fmaxf(acc[i][2][r], acc[i][3][r]));
      mx = fmaxf(mx, __shfl_xor(mx, 1));
      mx = fmaxf(mx, __shfl_xor(mx, 2));
      mx = fmaxf(mx, __shfl_xor(mx, 4));
      mx = fmaxf(mx, __shfl_xor(mx, 8));
      if (l16 == 0) wred[i * 16 + kh * 4 + r][wave] = mx;
    }
  __syncthreads();

#pragma unroll
  for (int i = 0; i < 4; ++i)
#pragma unroll
    for (int r = 0; r < 4; ++r) {
      int row = i * 16 + kh * 4 + r;
      float gm = fmaxf(fmaxf(wred[row][0], wred[row][1]),
                       fmaxf(wred[row][2], wred[row][3]));
      float s = 0.0f;
#pragma unroll
      for (int j = 0; j < 4; ++j) {
        float e = expf(acc[i][j][r] - gm);
        acc[i][j][r] = e;
        s += e;
      }
      s += __shfl_xor(s, 1);
      s += __shfl_xor(s, 2);
      s += __shfl_xor(s, 4);
      s += __shfl_xor(s, 8);
      if (l16 == 0) wsum[row][wave] = s;
    }
  __syncthreads();

#pragma unroll
  for (int i = 0; i < 4; ++i)
#pragma unroll
    for (int r = 0; r < 4; ++r) {
      int row = i * 16 + kh * 4 + r;
      float inv = 1.0f / (wsum[row][0] + wsum[row][1] + wsum[row][2] + wsum[row][3]);
#pragma unroll
      for (int j = 0; j < 4; ++j)
        P[row * 264 + wave * 64 + j * 16 + l16] = __float2bfloat16(acc[i][j][r] * inv);
    }
  __syncthreads();

  // O = P @ xqV ; fused gate epilogue against G1 (resident in out)
  for (int nb = 0; nb < 3; ++nb) {
    const int n0 = nb * 256 + wave * 64;
    const bf16* btp = xqVT + ((long)b * 768 + n0) * 256;
    f32x4 a2[4][4] = {};
#pragma unroll
    for (int kk = 0; kk < 256; kk += 32) {
      bf16x8 pf[4], vf[4];
#pragma unroll
      for (int i = 0; i < 4; ++i)
        pf[i] = ld_frag(P + (i * 16 + l16) * 264 + kk + kh * 8);
#pragma unroll
      for (int j = 0; j < 4; ++j)
        vf[j] = ld_frag(btp + (j * 16 + l16) * 256 + kk + kh * 8);
#pragma unroll
      for (int i = 0; i < 4; ++i)
#pragma unroll
        for (int j = 0; j < 4; ++j)
          a2[i][j] = mfma_bf16(pf[i], vf[j], a2[i][j]);
    }
#pragma unroll
    for (int i = 0; i < 4; ++i)
#pragma unroll
      for (int j = 0; j < 4; ++j)
#pragma unroll
        for (int r = 0; r < 4; ++r) {
          long row = crow0 + i * 16 + kh * 4 + r;
          int col = n0 + j * 16 + l16;
          float v = a2[i][j][r] + out[row * 768 + col];
          out[row * 768 + col] = 1.0f / (1.0f + __expf(-v));
        }
  }
}

extern "C" void kernel_launch(void* const* d_in, const int* in_sizes, int n_in,
                              void* d_out, int out_size, void* d_ws, size_t ws_size,
                              hipStream_t stream) {
  const float* x_cont = (const float*)d_in[0];  // [16,2048,768]
  const float* x_ques = (const float*)d_in[1];  // [16,256,768]
  const int* ques_len = (const int*)d_in[2];    // [16]
  const float* WC = (const float*)d_in[3];      // [768,768]
  const float* WQ = (const float*)d_in[4];      // [768,768]
  const float* V = (const float*)d_in[5];       // [1536,768]
  float* out = (float*)d_out;                   // [32768,768] f32 (holds G1 mid-pipeline)

  // ws layout (bf16 elements), ~133 MB total
  bf16* Wct = (bf16*)d_ws;                       // [1536][768] = [WC^T ; Vtop^T]
  bf16* Wqt = Wct + (long)1536 * 768;            // [1536][768] = [WQ^T ; Vbot^T]
  bf16* xcB = Wqt + (long)1536 * 768;            // [32768][768]
  bf16* xqB = xcB + (long)32768 * 768;           // [4096][768]
  bf16* xcW = xqB + (long)4096 * 768;            // [32768][768]
  bf16* xqW = xcW + (long)32768 * 768;           // [4096][768]
  bf16* xqV = xqW + (long)4096 * 768;            // [4096][768]
  bf16* xqVT = xqV + (long)4096 * 768;           // [16][768][256]

  (void)hipFuncSetAttribute(reinterpret_cast<const void*>(&gemm4b),
                            hipFuncAttributeMaxDynamicSharedMemorySize, 131072);

  // weight prep: Wct = [WC^T ; Vtop^T], Wqt = [WQ^T ; Vbot^T]
  transpose_f32_bf16<<<dim3(24, 24), dim3(32, 8), 0, stream>>>(WC, Wct, 768, 768);
  transpose_f32_bf16<<<dim3(24, 24), dim3(32, 8), 0, stream>>>(
      V, Wct + (long)768 * 768, 768, 768);
  transpose_f32_bf16<<<dim3(24, 24), dim3(32, 8), 0, stream>>>(WQ, Wqt, 768, 768);
  transpose_f32_bf16<<<dim3(24, 24), dim3(32, 8), 0, stream>>>(
      V + (long)768 * 768, Wqt + (long)768 * 768, 768, 768);

  // input converts
  convert_flat<<<24576, 256, 0, stream>>>(x_cont, xcB, (long)32768 * 768 / 4);
  convert_flat<<<3072, 256, 0, stream>>>(x_ques, xqB, (long)4096 * 768 / 4);

  // xq fused projection: [xqW | xqV] = relu/id(xq @ [WQ | Vbot])
  gemm_bt_split<<<dim3(32, 12), 256, 0, stream>>>(xqB, 768, Wqt, 768, xqW, xqV, 768);
  // xqV -> xqVT (per batch [256][768] -> [768][256])
  transpose_bf16<<<dim3(24, 8, 16), dim3(32, 8), 0, stream>>>(
      xqV, xqVT, 256, 768, (long)256 * 768, (long)768 * 256);

  // xc fused projection: xcW (relu bf16) + G1 (f32, into d_out)
  gemm4b<<<768, 512, 131072, stream>>>(xcB, 768, Wct, 768, xcW, out, 768);

  // attention + gate epilogue
  attn_kernel<<<dim3(32, 16), 256, 0, stream>>>(xcW, xqW, xqVT, ques_len, out);
}

// Round 4
// 255.716 us; speedup vs baseline: 1.3357x; 1.1254x over previous
//
#include <hip/hip_runtime.h>
#include <hip/hip_bf16.h>
#include <cstdint>

// GateAttention, restructured:
//   xcW|G1 = xc @ [WC | V_top]   (relu on xcW half; G1 bf16 -> ws)
//   xqW|xqV = xq @ [WQ | V_bot]  (relu on xqW half)
//   attn: S = xcW.xqW^T, softmax+mask, O = P @ xqV, out = sigmoid(G1 + O)
// Round 4: bf16 G1; attn 128-row/8-wave blocks with dbuf QK (vmcnt(3) ledger),
// hoisted P fragments in PV, XCD-chunked batch placement.
// B=16, LC=2048, LQ=256, D=768, F=768.

using bf16 = __hip_bfloat16;
typedef __attribute__((ext_vector_type(8))) __bf16 bf16x8;
typedef __attribute__((ext_vector_type(4))) float f32x4;

typedef __attribute__((address_space(1))) const uint32_t GU32;
typedef __attribute__((address_space(3))) uint32_t LU32;

__device__ __forceinline__ void gll16(const bf16* g, bf16* l) {
  __builtin_amdgcn_global_load_lds((GU32*)g, (LU32*)l, 16, 0, 0);
}
__device__ __forceinline__ f32x4 mfma_bf16(bf16x8 a, bf16x8 b, f32x4 c) {
  return __builtin_amdgcn_mfma_f32_16x16x32_bf16(a, b, c, 0, 0, 0);
}
__device__ __forceinline__ bf16x8 ld_frag(const bf16* p) {
  return *reinterpret_cast<const bf16x8*>(p);
}
// LDS chunk swizzle: conflict-free for stride-64B rows under 8-lane beats.
__device__ __forceinline__ int swz(int r) { return (r & 3) ^ ((r >> 2) & 1); }

__device__ __forceinline__ unsigned short f2bf_bits(float x) {
  bf16 b = __float2bfloat16(x);
  union { bf16 b; unsigned short s; } u;
  u.b = b;
  return u.s;
}

// ---------- transpose f32 [R][C] -> bf16 [C][R] ----------
__global__ void transpose_f32_bf16(const float* __restrict__ in, bf16* __restrict__ out,
                                   int R, int C) {
  __shared__ float tile[32][33];
  int c0 = blockIdx.x * 32, r0 = blockIdx.y * 32;
  int tx = threadIdx.x, ty = threadIdx.y;
#pragma unroll
  for (int i = ty; i < 32; i += 8)
    tile[i][tx] = in[(long)(r0 + i) * C + (c0 + tx)];
  __syncthreads();
#pragma unroll
  for (int i = ty; i < 32; i += 8)
    out[(long)(c0 + i) * R + (r0 + tx)] = __float2bfloat16(tile[tx][i]);
}

// ---------- transpose bf16 [R][C] -> bf16 [C][R], batched ----------
__global__ void transpose_bf16(const bf16* __restrict__ in, bf16* __restrict__ out,
                               int R, int C, long ibs, long obs) {
  __shared__ bf16 tile[32][33];
  const bf16* inb = in + (long)blockIdx.z * ibs;
  bf16* outb = out + (long)blockIdx.z * obs;
  int c0 = blockIdx.x * 32, r0 = blockIdx.y * 32;
  int tx = threadIdx.x, ty = threadIdx.y;
#pragma unroll
  for (int i = ty; i < 32; i += 8)
    tile[i][tx] = inb[(long)(r0 + i) * C + (c0 + tx)];
  __syncthreads();
#pragma unroll
  for (int i = ty; i < 32; i += 8)
    outb[(long)(c0 + i) * R + (r0 + tx)] = tile[tx][i];
}

// ---------- flat f32 -> bf16 convert, 8B stores ----------
__global__ void convert_flat(const float* __restrict__ in, bf16* __restrict__ out, long n4) {
  long i = (long)blockIdx.x * blockDim.x + threadIdx.x;
  if (i >= n4) return;
  float4 v = reinterpret_cast<const float4*>(in)[i];
  ushort4 o;
  o.x = f2bf_bits(v.x);
  o.y = f2bf_bits(v.y);
  o.z = f2bf_bits(v.z);
  o.w = f2bf_bits(v.w);
  reinterpret_cast<ushort4*>(out)[i] = o;
}

// ---------- 128x128 GEMM with split epilogue (small xq projection) ----------
__global__ __launch_bounds__(256) void gemm_bt_split(
    const bf16* __restrict__ A, long lda,
    const bf16* __restrict__ Bt, long ldb,
    bf16* __restrict__ O1, bf16* __restrict__ O2, int K) {
  __shared__ __align__(16) bf16 As[128 * 32];
  __shared__ __align__(16) bf16 Bs[128 * 32];
  const int tid = threadIdx.x;
  const int wave = tid >> 6;
  const int lane = tid & 63;
  const int l16 = lane & 15;
  const int kh = lane >> 4;
  const int wm = (wave >> 1) * 64;
  const int wn = (wave & 1) * 64;
  const long row0 = (long)blockIdx.x * 128;
  const long col0 = (long)blockIdx.y * 128;
  const int srow = tid >> 2;
  const int scol = ((tid & 3) ^ swz(srow)) * 8;

  const bf16* ap0 = A + (row0 + srow) * lda + scol;
  const bf16* ap1 = ap0 + 64 * lda;
  const bf16* bp0 = Bt + (col0 + srow) * ldb + scol;
  const bf16* bp1 = bp0 + 64 * ldb;
  bf16* as0 = As + wave * 512;
  bf16* as1 = as0 + 2048;
  bf16* bs0 = Bs + wave * 512;
  bf16* bs1 = bs0 + 2048;

  const int xc = (kh ^ swz(l16)) * 8;
  f32x4 acc[4][4] = {};

  for (int k0 = 0; k0 < K; k0 += 32) {
    gll16(ap0 + k0, as0);
    gll16(ap1 + k0, as1);
    gll16(bp0 + k0, bs0);
    gll16(bp1 + k0, bs1);
    __syncthreads();
    bf16x8 af[4], bfr[4];
#pragma unroll
    for (int i = 0; i < 4; ++i)
      af[i] = ld_frag(As + (wm + i * 16 + l16) * 32 + xc);
#pragma unroll
    for (int j = 0; j < 4; ++j)
      bfr[j] = ld_frag(Bs + (wn + j * 16 + l16) * 32 + xc);
#pragma unroll
    for (int i = 0; i < 4; ++i)
#pragma unroll
      for (int j = 0; j < 4; ++j)
        acc[i][j] = mfma_bf16(af[i], bfr[j], acc[i][j]);
    __syncthreads();
  }

  const bool isO1 = col0 < 768;
#pragma unroll
  for (int i = 0; i < 4; ++i)
#pragma unroll
    for (int j = 0; j < 4; ++j)
#pragma unroll
      for (int r = 0; r < 4; ++r) {
        long row = row0 + wm + i * 16 + kh * 4 + r;
        long col = col0 + wn + j * 16 + l16;
        float v = acc[i][j][r];
        if (isO1)
          O1[row * 768 + col] = __float2bfloat16(fmaxf(v, 0.0f));
        else
          O2[row * 768 + (col - 768)] = __float2bfloat16(v);
      }
}

// ---------- 256x256 GEMM, BK=32, 4-buffer LDS, 3-tile prefetch depth -------
// cols [0,768): relu -> O1 bf16 (xcW) ; cols [768,1536): plain -> O2 bf16 (G1).
__global__ __launch_bounds__(512, 2) void gemm4b(
    const bf16* __restrict__ A, long lda,
    const bf16* __restrict__ Bt, long ldb,
    bf16* __restrict__ O1, bf16* __restrict__ O2, int K) {
  extern __shared__ __align__(16) bf16 smem[];  // 4 bufs x (A 8192 + B 8192) bf16
  const int tid = threadIdx.x;
  const int wid = tid >> 6;
  const int lane = tid & 63;
  const int l15 = lane & 15;
  const int g = lane >> 4;
  const int wm = wid >> 2;
  const int wn = wid & 3;

  const int lin = blockIdx.x;          // 0..767
  const int per = (int)gridDim.x >> 3; // 96
  const int wgid = (lin & 7) * per + (lin >> 3);
  const long row0 = (long)(wgid / 6) * 256;
  const long col0 = (long)(wgid % 6) * 256;

  const int srow = lane >> 2;
  const int sc = ((lane & 3) ^ swz(srow)) * 8;
  const int w16 = wid * 16;
  const bf16* Ab = A + (row0 + srow) * lda + sc;
  const bf16* Bb = Bt + (col0 + srow) * ldb + sc;

  f32x4 acc[8][4] = {};

  auto stageA = [&](int buf, int kk) {
    bf16* d = smem + buf * 16384 + w16 * 32;
    gll16(Ab + (long)w16 * lda + kk, d);
    gll16(Ab + (long)(128 + w16) * lda + kk, d + 128 * 32);
  };
  auto stageB = [&](int buf, int kk) {
    bf16* d = smem + buf * 16384 + 8192 + w16 * 32;
    gll16(Bb + (long)w16 * ldb + kk, d);
    gll16(Bb + (long)(128 + w16) * ldb + kk, d + 128 * 32);
  };
  const int xc = (g ^ swz(l15)) * 8;
  auto ldA = [&](int buf, int m) {
    int row = wm * 128 + m * 16 + l15;
    return ld_frag(smem + buf * 16384 + row * 32 + xc);
  };
  auto ldB = [&](int buf, int n) {
    int row = wn * 64 + n * 16 + l15;
    return ld_frag(smem + buf * 16384 + 8192 + row * 32 + xc);
  };

  stageA(0, 0);
  stageB(0, 0);
  stageA(1, 32);
  stageB(1, 32);
  stageA(2, 64);
  stageB(2, 64);
  asm volatile("s_waitcnt vmcnt(8)\n\ts_barrier" ::: "memory");

  const int NT = K >> 5;  // 24
  bf16x8 av[4], bv[4];

  for (int t = 0; t < NT; ++t) {
    const int cur = t & 3;
    const int pfb = (t + 3) & 3;
    const bool pf = (t + 3) < NT;
    const int kk = (t + 3) << 5;

#pragma unroll
    for (int n = 0; n < 4; ++n) bv[n] = ldB(cur, n);
#pragma unroll
    for (int m = 0; m < 4; ++m) av[m] = ldA(cur, m);
    if (pf) stageA(pfb, kk);
    __builtin_amdgcn_s_barrier();
    __builtin_amdgcn_s_setprio(1);
#pragma unroll
    for (int m = 0; m < 4; ++m)
#pragma unroll
      for (int n = 0; n < 4; ++n) acc[m][n] = mfma_bf16(av[m], bv[n], acc[m][n]);
    __builtin_amdgcn_s_setprio(0);
    __builtin_amdgcn_s_barrier();

#pragma unroll
    for (int m = 0; m < 4; ++m) av[m] = ldA(cur, 4 + m);
    if (pf) stageB(pfb, kk);
    __builtin_amdgcn_s_barrier();
    __builtin_amdgcn_s_setprio(1);
#pragma unroll
    for (int m = 0; m < 4; ++m)
#pragma unroll
      for (int n = 0; n < 4; ++n)
        acc[4 + m][n] = mfma_bf16(av[m], bv[n], acc[4 + m][n]);
    __builtin_amdgcn_s_setprio(0);

    if (t <= NT - 4)
      asm volatile("s_waitcnt vmcnt(8)\n\ts_barrier" ::: "memory");
    else if (t == NT - 3)
      asm volatile("s_waitcnt vmcnt(4)\n\ts_barrier" ::: "memory");
    else if (t == NT - 2)
      asm volatile("s_waitcnt vmcnt(0)\n\ts_barrier" ::: "memory");
  }

  const bool isO1 = col0 < 768;
#pragma unroll
  for (int m = 0; m < 8; ++m)
#pragma unroll
    for (int n = 0; n < 4; ++n)
#pragma unroll
      for (int r = 0; r < 4; ++r) {
        long row = row0 + wm * 128 + m * 16 + g * 4 + r;
        long col = col0 + wn * 64 + n * 16 + l15;
        float v = acc[m][n][r];
        if (isO1)
          O1[row * 768 + col] = __float2bfloat16(fmaxf(v, 0.0f));
        else
          O2[row * 768 + (col - 768)] = __float2bfloat16(v);
      }
}

// ---------- fused attention + gate: 128 c-rows per block, 8 waves ----------
// Wave (wr,wc) = (wid>>2, wid&3). QK: dbuf LDS, counted vmcnt(3).
// dyn LDS layout (bf16 el): As[2][4096] @0, Bs[2][8192] @8192, P[128*264]
// @24576; floats wred[128][4] @byte 116736, wsum[128][4] @118784. 120832 B.
__global__ __launch_bounds__(512, 2) void attn_kernel(
    const bf16* __restrict__ xcW, const bf16* __restrict__ xqW,
    const bf16* __restrict__ xqVT, const bf16* __restrict__ G1,
    const int* __restrict__ qlen_arr, float* __restrict__ out) {
  extern __shared__ __align__(16) bf16 smem[];
  bf16* P = smem + 24576;
  float* wred = (float*)(smem + 58368);   // [128][4]
  float* wsum = wred + 512;               // [128][4]

  // XCD-chunked placement: XCD x serves batches 2x, 2x+1.
  const int n = blockIdx.x;       // 0..255
  const int xcd = n & 7;
  const int idx = n >> 3;         // 0..31
  const int b = xcd * 2 + (idx >> 4);
  const int ct = idx & 15;

  const int tid = threadIdx.x;
  const int wid = tid >> 6;
  const int lane = tid & 63;
  const int l16 = lane & 15;
  const int kh = lane >> 4;
  const int wr = wid >> 2;   // 0..1
  const int wc = wid & 3;    // 0..3

  const long crow0 = (long)b * 2048 + (long)ct * 128;
  const int srow = lane >> 2;
  const int sc = ((lane & 3) ^ swz(srow)) * 8;
  const int xcr = (kh ^ swz(l16)) * 8;

  const bf16* ap = xcW + (crow0 + wid * 16 + srow) * 768 + sc;
  const bf16* bp = xqW + ((long)b * 256 + wid * 32 + srow) * 768 + sc;
  const bf16* bp2 = bp + 16 * 768;

  auto stage = [&](int bufi, int k0) {
    gll16(ap + k0, smem + bufi * 4096 + wid * 512);
    gll16(bp + k0, smem + 8192 + bufi * 8192 + wid * 1024);
    gll16(bp2 + k0, smem + 8192 + bufi * 8192 + wid * 1024 + 512);
  };

  f32x4 acc[4][4] = {};
  stage(0, 0);

  for (int t = 0; t < 24; ++t) {
    const int cur = t & 1;
    if (t + 1 < 24) {
      stage(cur ^ 1, (t + 1) * 32);
      asm volatile("s_waitcnt vmcnt(3)\n\ts_barrier" ::: "memory");
    } else {
      asm volatile("s_waitcnt vmcnt(0)\n\ts_barrier" ::: "memory");
    }
    const bf16* Ac = smem + cur * 4096;
    const bf16* Bc = smem + 8192 + cur * 8192;
    bf16x8 af[4], bfr[4];
#pragma unroll
    for (int i = 0; i < 4; ++i)
      af[i] = ld_frag(Ac + (wr * 64 + i * 16 + l16) * 32 + xcr);
#pragma unroll
    for (int j = 0; j < 4; ++j)
      bfr[j] = ld_frag(Bc + (wc * 64 + j * 16 + l16) * 32 + xcr);
    __builtin_amdgcn_s_setprio(1);
#pragma unroll
    for (int i = 0; i < 4; ++i)
#pragma unroll
      for (int j = 0; j < 4; ++j)
        acc[i][j] = mfma_bf16(af[i], bfr[j], acc[i][j]);
    __builtin_amdgcn_s_setprio(0);
    __builtin_amdgcn_s_barrier();
  }

  const float scale = 0.036084391824351615f;  // 1/sqrt(768)
  const int qlen = qlen_arr[b];

#pragma unroll
  for (int i = 0; i < 4; ++i)
#pragma unroll
    for (int j = 0; j < 4; ++j) {
      int col = wc * 64 + j * 16 + l16;
      float m = (col >= qlen) ? -1.0e12f : 0.0f;
#pragma unroll
      for (int r = 0; r < 4; ++r)
        acc[i][j][r] = acc[i][j][r] * scale + m;
    }

#pragma unroll
  for (int i = 0; i < 4; ++i)
#pragma unroll
    for (int r = 0; r < 4; ++r) {
      float mx = fmaxf(fmaxf(acc[i][0][r], acc[i][1][r]),
                       fmaxf(acc[i][2][r], acc[i][3][r]));
      mx = fmaxf(mx, __shfl_xor(mx, 1));
      mx = fmaxf(mx, __shfl_xor(mx, 2));
      mx = fmaxf(mx, __shfl_xor(mx, 4));
      mx = fmaxf(mx, __shfl_xor(mx, 8));
      if (l16 == 0) wred[(wr * 64 + i * 16 + kh * 4 + r) * 4 + wc] = mx;
    }
  __syncthreads();

#pragma unroll
  for (int i = 0; i < 4; ++i)
#pragma unroll
    for (int r = 0; r < 4; ++r) {
      int row = wr * 64 + i * 16 + kh * 4 + r;
      float gm = fmaxf(fmaxf(wred[row * 4 + 0], wred[row * 4 + 1]),
                       fmaxf(wred[row * 4 + 2], wred[row * 4 + 3]));
      float s = 0.0f;
#pragma unroll
      for (int j = 0; j < 4; ++j) {
        float e = expf(acc[i][j][r] - gm);
        acc[i][j][r] = e;
        s += e;
      }
      s += __shfl_xor(s, 1);
      s += __shfl_xor(s, 2);
      s += __shfl_xor(s, 4);
      s += __shfl_xor(s, 8);
      if (l16 == 0) wsum[row * 4 + wc] = s;
    }
  __syncthreads();

#pragma unroll
  for (int i = 0; i < 4; ++i)
#pragma unroll
    for (int r = 0; r < 4; ++r) {
      int row = wr * 64 + i * 16 + kh * 4 + r;
      float inv = 1.0f / (wsum[row * 4 + 0] + wsum[row * 4 + 1] +
                          wsum[row * 4 + 2] + wsum[row * 4 + 3]);
#pragma unroll
      for (int j = 0; j < 4; ++j)
        P[row * 264 + wc * 64 + j * 16 + l16] = __float2bfloat16(acc[i][j][r] * inv);
    }
  __syncthreads();

  // hoist P fragments (reused across all 3 nb sweeps)
  bf16x8 pf[4][8];
#pragma unroll
  for (int i = 0; i < 4; ++i)
#pragma unroll
    for (int kk = 0; kk < 8; ++kk)
      pf[i][kk] = ld_frag(P + (wr * 64 + i * 16 + l16) * 264 + kk * 32 + kh * 8);

  for (int nb = 0; nb < 3; ++nb) {
    const int n0 = nb * 256 + wc * 64;
    const bf16* btp = xqVT + ((long)b * 768 + n0) * 256;
    f32x4 a2[4][4] = {};
#pragma unroll
    for (int kk = 0; kk < 8; ++kk) {
      bf16x8 vf[4];
#pragma unroll
      for (int j = 0; j < 4; ++j)
        vf[j] = ld_frag(btp + (j * 16 + l16) * 256 + kk * 32 + kh * 8);
#pragma unroll
      for (int i = 0; i < 4; ++i)
#pragma unroll
        for (int j = 0; j < 4; ++j)
          a2[i][j] = mfma_bf16(pf[i][kk], vf[j], a2[i][j]);
    }
#pragma unroll
    for (int i = 0; i < 4; ++i)
#pragma unroll
      for (int j = 0; j < 4; ++j)
#pragma unroll
        for (int r = 0; r < 4; ++r) {
          long row = crow0 + wr * 64 + i * 16 + kh * 4 + r;
          int col = n0 + j * 16 + l16;
          float v = a2[i][j][r] + __bfloat162float(G1[row * 768 + col]);
          out[row * 768 + col] = 1.0f / (1.0f + __expf(-v));
        }
  }
}

extern "C" void kernel_launch(void* const* d_in, const int* in_sizes, int n_in,
                              void* d_out, int out_size, void* d_ws, size_t ws_size,
                              hipStream_t stream) {
  const float* x_cont = (const float*)d_in[0];  // [16,2048,768]
  const float* x_ques = (const float*)d_in[1];  // [16,256,768]
  const int* ques_len = (const int*)d_in[2];    // [16]
  const float* WC = (const float*)d_in[3];      // [768,768]
  const float* WQ = (const float*)d_in[4];      // [768,768]
  const float* V = (const float*)d_in[5];       // [1536,768]
  float* out = (float*)d_out;                   // [32768,768] f32

  // ws layout (bf16 elements), ~172.5 MB total
  bf16* Wct = (bf16*)d_ws;                       // [1536][768] = [WC^T ; Vtop^T]
  bf16* Wqt = Wct + (long)1536 * 768;            // [1536][768] = [WQ^T ; Vbot^T]
  bf16* xcB = Wqt + (long)1536 * 768;            // [32768][768]
  bf16* xqB = xcB + (long)32768 * 768;           // [4096][768]
  bf16* xcW = xqB + (long)4096 * 768;            // [32768][768]
  bf16* xqW = xcW + (long)32768 * 768;           // [4096][768]
  bf16* xqV = xqW + (long)4096 * 768;            // [4096][768]
  bf16* xqVT = xqV + (long)4096 * 768;           // [16][768][256]
  bf16* G1 = xqVT + (long)16 * 768 * 256;        // [32768][768]

  (void)hipFuncSetAttribute(reinterpret_cast<const void*>(&gemm4b),
                            hipFuncAttributeMaxDynamicSharedMemorySize, 131072);
  (void)hipFuncSetAttribute(reinterpret_cast<const void*>(&attn_kernel),
                            hipFuncAttributeMaxDynamicSharedMemorySize, 131072);

  // weight prep: Wct = [WC^T ; Vtop^T], Wqt = [WQ^T ; Vbot^T]
  transpose_f32_bf16<<<dim3(24, 24), dim3(32, 8), 0, stream>>>(WC, Wct, 768, 768);
  transpose_f32_bf16<<<dim3(24, 24), dim3(32, 8), 0, stream>>>(
      V, Wct + (long)768 * 768, 768, 768);
  transpose_f32_bf16<<<dim3(24, 24), dim3(32, 8), 0, stream>>>(WQ, Wqt, 768, 768);
  transpose_f32_bf16<<<dim3(24, 24), dim3(32, 8), 0, stream>>>(
      V + (long)768 * 768, Wqt + (long)768 * 768, 768, 768);

  // input converts
  convert_flat<<<24576, 256, 0, stream>>>(x_cont, xcB, (long)32768 * 768 / 4);
  convert_flat<<<3072, 256, 0, stream>>>(x_ques, xqB, (long)4096 * 768 / 4);

  // xq fused projection: [xqW | xqV] = relu/id(xq @ [WQ | Vbot])
  gemm_bt_split<<<dim3(32, 12), 256, 0, stream>>>(xqB, 768, Wqt, 768, xqW, xqV, 768);
  transpose_bf16<<<dim3(24, 8, 16), dim3(32, 8), 0, stream>>>(
      xqV, xqVT, 256, 768, (long)256 * 768, (long)768 * 256);

  // xc fused projection: xcW (relu bf16) + G1 (bf16)
  gemm4b<<<768, 512, 131072, stream>>>(xcB, 768, Wct, 768, xcW, G1, 768);

  // attention + gate epilogue
  attn_kernel<<<256, 512, 120832, stream>>>(xcW, xqW, xqVT, G1, ques_len, out);
}